// Round 4
// baseline (109.105 us; speedup 1.0000x reference)
//
#include <hip/hip_runtime.h>
#include <math.h>

#define TOK 12544   // B*H*W
#define CDIM 128
#define NHEAD 4
#define HD 32
#define KS 7
#define HSZ 56
#define WSZ 56

typedef __attribute__((ext_vector_type(8))) short short8;   // bf16x8 mfma frag
typedef __attribute__((ext_vector_type(4))) float f32x4;

__device__ inline ushort f2b(float f) {                      // fp32 -> bf16 RNE
    uint u = __float_as_uint(f);
    u += 0x7fffu + ((u >> 16) & 1u);
    return (ushort)(u >> 16);
}

// ---------- convert the 4 weight matrices to bf16 into one contiguous buffer ----------
__global__ void convert_w(const float* __restrict__ a, const float* __restrict__ b,
                          const float* __restrict__ c, const float* __restrict__ d,
                          ushort* __restrict__ wb) {
    int e = (blockIdx.x * 256 + threadIdx.x) * 4;
    const float* src;
    if (e < 49152)       src = a + e;
    else if (e < 65536)  src = b + (e - 49152);
    else if (e < 131072) src = c + (e - 65536);
    else                 src = d + (e - 131072);
    float4 v = *(const float4*)src;
    uint2 pk;
    pk.x = (uint)f2b(v.x) | ((uint)f2b(v.y) << 16);
    pk.y = (uint)f2b(v.z) | ((uint)f2b(v.w) << 16);
    *(uint2*)(wb + e) = pk;
}

// ---------- Unified MFMA GEMM: tile 64(M) x 64(N), B staged in LDS (swizzled) ----------
// block = 256 thr (4 waves, 16 rows each). Optional fused LayerNorm on the input
// (LNIN): LN of the 64-row X tile -> swizzled LDS A, consumed by MFMA directly.
// EPI: 0 = qkv (scale cols<128 by 32^-0.5) -> f32; 1 = +res -> f32; 2 = GELU -> bf16
template<int N, int KD, int EPI, bool LNIN>
__global__ __launch_bounds__(256) void gemm2(const void* __restrict__ Xv,
                                             const ushort* __restrict__ W,
                                             const float* __restrict__ bias,
                                             const float* __restrict__ res,
                                             const float* __restrict__ lnw,
                                             const float* __restrict__ lnb,
                                             float* __restrict__ Yf,
                                             ushort* __restrict__ Yb) {
    __shared__ ushort Bl[64 * 128];                 // 16 KB, XOR-swizzled
    __shared__ ushort Al[LNIN ? 64 * 128 : 64];     // 16 KB when LN-fused
    int tid = threadIdx.x, wv = tid >> 6, lane = tid & 63;
    int lr = lane & 15, kg = lane >> 4;
    int m0 = blockIdx.x * 64, n0 = blockIdx.y * 64;

    if (LNIN) {
        const float* X = (const float*)Xv;
        for (int r = 0; r < 16; r++) {
            int rl = wv * 16 + r;
            float2 v = *(const float2*)(X + (size_t)(m0 + rl) * CDIM + lane * 2);
            float s = v.x + v.y;
            #pragma unroll
            for (int o = 32; o > 0; o >>= 1) s += __shfl_xor(s, o);
            float mu = s * (1.0f / 128.0f);
            float d0 = v.x - mu, d1 = v.y - mu;
            float sq = d0 * d0 + d1 * d1;
            #pragma unroll
            for (int o = 32; o > 0; o >>= 1) sq += __shfl_xor(sq, o);
            float rstd = rsqrtf(sq * (1.0f / 128.0f) + 1e-5f);
            float2 wv2 = *(const float2*)(lnw + lane * 2);
            float2 bv2 = *(const float2*)(lnb + lane * 2);
            float o0 = d0 * rstd * wv2.x + bv2.x;
            float o1 = d1 * rstd * wv2.y + bv2.y;
            uint pk = (uint)f2b(o0) | ((uint)f2b(o1) << 16);
            *(uint*)((char*)Al + rl * 256 + ((lane * 4) ^ ((rl & 7) << 4))) = pk;
        }
    }

    f32x4 acc[4] = {};
    const ushort* Xb = (const ushort*)Xv;

    #pragma unroll
    for (int ks = 0; ks < KD / 128; ks++) {
        __syncthreads();
        // stage B slice [n0..n0+64) x [ks*128..+128) into swizzled LDS
        #pragma unroll
        for (int c = 0; c < 4; c++) {
            int ch = c * 256 + tid;        // 0..1023 16B-chunks
            int row = ch >> 4, sl = ch & 15;
            uint4 d = *(const uint4*)(W + (size_t)(n0 + row) * KD + ks * 128 + sl * 8);
            *(uint4*)((char*)Bl + row * 256 + ((sl * 16) ^ ((row & 7) << 4))) = d;
        }
        __syncthreads();

        int rl = wv * 16 + lr;
        #pragma unroll
        for (int k0 = 0; k0 < 128; k0 += 32) {
            short8 a0;
            if (LNIN)
                a0 = *(const short8*)((char*)Al + rl * 256 + ((k0 * 2 + kg * 16) ^ ((rl & 7) << 4)));
            else
                a0 = *(const short8*)(Xb + (size_t)(m0 + rl) * KD + ks * 128 + k0 + kg * 8);
            #pragma unroll
            for (int ni = 0; ni < 4; ni++) {
                int br = ni * 16 + lr;
                short8 bf = *(const short8*)((char*)Bl + br * 256 + ((k0 * 2 + kg * 16) ^ ((br & 7) << 4)));
                acc[ni] = __builtin_amdgcn_mfma_f32_16x16x32_bf16(a0, bf, acc[ni], 0, 0, 0);
            }
        }
    }

    #pragma unroll
    for (int ni = 0; ni < 4; ni++) {
        int col = n0 + ni * 16 + lr;
        float bn = bias[col];
        #pragma unroll
        for (int r = 0; r < 4; r++) {
            int row = m0 + wv * 16 + kg * 4 + r;
            size_t o = (size_t)row * N + col;
            float v = acc[ni][r] + bn;
            if (EPI == 0) {
                if (col < CDIM) v *= 0.17677669529663687f;   // q pre-scale 32^-0.5
                Yf[o] = v;
            } else if (EPI == 1) {
                Yf[o] = v + res[o];
            } else {
                Yb[o] = f2b(0.5f * v * (1.0f + erff(v * 0.70710678118654752f)));
            }
        }
    }
}

// ---------- Neighborhood attention v3 (validated R2): scores live in LDS ----------
__global__ void nat_attn3(const float* __restrict__ qkv, const float* __restrict__ rpb,
                          ushort* __restrict__ ao) {
    __shared__ float ks[196][36];
    __shared__ float vs[196][36];
    __shared__ float att[64][53];
    int tid  = threadIdx.x;
    int blk  = blockIdx.x;
    int tile = blk % 49;
    int hb   = blk / 49;
    int head = hb & 3;
    int b    = hb >> 2;
    int r0 = (tile / 7) * 8, c0 = (tile % 7) * 8;
    int hr0 = min(max(r0 - 3, 0), HSZ - 14);
    int hc0 = min(max(c0 - 3, 0), WSZ - 14);

    const float* kbase = qkv + (size_t)b * HSZ * WSZ * 384 + 128 + head * HD;
    for (int idx = tid; idx < 196 * 8; idx += 256) {
        int t = idx >> 3, f = idx & 7;
        int gtok = (hr0 + t / 14) * WSZ + hc0 + t % 14;
        const float* tp = kbase + (size_t)gtok * 384 + f * 4;
        *(float4*)&ks[t][f * 4] = *(const float4*)tp;
        *(float4*)&vs[t][f * 4] = *(const float4*)(tp + 128);
    }
    __syncthreads();

    int p = tid >> 2, s = tid & 3;
    int pi = p >> 3, pj = p & 7;
    int i = r0 + pi, j = c0 + pj;
    int shh = min(max(i - 3, 0), HSZ - KS);
    int sww = min(max(j - 3, 0), WSZ - KS);
    int di = shh - hr0, dj = sww - hc0;
    int gp = (b * HSZ + i) * WSZ + j;

    const float* qp = qkv + (size_t)gp * 384 + head * HD;
    float4 q0 = *(const float4*)(qp +  0), q1 = *(const float4*)(qp +  4);
    float4 q2 = *(const float4*)(qp +  8), q3 = *(const float4*)(qp + 12);
    float4 q4 = *(const float4*)(qp + 16), q5 = *(const float4*)(qp + 20);
    float4 q6 = *(const float4*)(qp + 24), q7 = *(const float4*)(qp + 28);
    const float* bp = rpb + head * 169 + (shh - i + 6) * 13 + (sww - j + 6);

    for (int it = 0; it < 13; it++) {
        int l = it * 4 + s;
        if (l < 49) {
            int ki = l / 7, kj = l % 7;
            const float* kr = &ks[(di + ki) * 14 + dj + kj][0];
            float4 k4;
            float a = 0.f;
            k4 = *(const float4*)(kr +  0); a += q0.x*k4.x + q0.y*k4.y + q0.z*k4.z + q0.w*k4.w;
            k4 = *(const float4*)(kr +  4); a += q1.x*k4.x + q1.y*k4.y + q1.z*k4.z + q1.w*k4.w;
            k4 = *(const float4*)(kr +  8); a += q2.x*k4.x + q2.y*k4.y + q2.z*k4.z + q2.w*k4.w;
            k4 = *(const float4*)(kr + 12); a += q3.x*k4.x + q3.y*k4.y + q3.z*k4.z + q3.w*k4.w;
            k4 = *(const float4*)(kr + 16); a += q4.x*k4.x + q4.y*k4.y + q4.z*k4.z + q4.w*k4.w;
            k4 = *(const float4*)(kr + 20); a += q5.x*k4.x + q5.y*k4.y + q5.z*k4.z + q5.w*k4.w;
            k4 = *(const float4*)(kr + 24); a += q6.x*k4.x + q6.y*k4.y + q6.z*k4.z + q6.w*k4.w;
            k4 = *(const float4*)(kr + 28); a += q7.x*k4.x + q7.y*k4.y + q7.z*k4.z + q7.w*k4.w;
            att[p][l] = a + bp[ki * 13 + kj];
        }
    }

    float m = -INFINITY;
    for (int it = 0; it < 13; it++) {
        int l = it * 4 + s;
        if (l < 49) m = fmaxf(m, att[p][l]);
    }
    m = fmaxf(m, __shfl_xor(m, 1));
    m = fmaxf(m, __shfl_xor(m, 2));
    float sum = 0.f;
    for (int it = 0; it < 13; it++) {
        int l = it * 4 + s;
        if (l < 49) {
            float e = __expf(att[p][l] - m);
            att[p][l] = e;
            sum += e;
        }
    }
    sum += __shfl_xor(sum, 1);
    sum += __shfl_xor(sum, 2);
    float inv = 1.0f / sum;
    __syncthreads();

    float oa[8] = {};
    #pragma unroll
    for (int ki = 0; ki < 7; ki++) {
        int rowb = (di + ki) * 14 + dj;
        #pragma unroll
        for (int kj = 0; kj < 7; kj++) {
            float a = att[p][ki * 7 + kj];
            const float* vr = &vs[rowb + kj][s * 8];
            float4 v0 = *(const float4*)vr;
            float4 v1 = *(const float4*)(vr + 4);
            oa[0] += a * v0.x; oa[1] += a * v0.y; oa[2] += a * v0.z; oa[3] += a * v0.w;
            oa[4] += a * v1.x; oa[5] += a * v1.y; oa[6] += a * v1.z; oa[7] += a * v1.w;
        }
    }
    uint4 pk;
    pk.x = (uint)f2b(oa[0] * inv) | ((uint)f2b(oa[1] * inv) << 16);
    pk.y = (uint)f2b(oa[2] * inv) | ((uint)f2b(oa[3] * inv) << 16);
    pk.z = (uint)f2b(oa[4] * inv) | ((uint)f2b(oa[5] * inv) << 16);
    pk.w = (uint)f2b(oa[6] * inv) | ((uint)f2b(oa[7] * inv) << 16);
    *(uint4*)(ao + (size_t)gp * CDIM + head * HD + s * 8) = pk;
}

extern "C" void kernel_launch(void* const* d_in, const int* in_sizes, int n_in,
                              void* d_out, int out_size, void* d_ws, size_t ws_size,
                              hipStream_t stream) {
    const float* x      = (const float*)d_in[0];
    const float* n1w    = (const float*)d_in[1];
    const float* n1b    = (const float*)d_in[2];
    const float* qkv_w  = (const float*)d_in[3];
    const float* qkv_b  = (const float*)d_in[4];
    const float* rpb    = (const float*)d_in[5];
    const float* proj_w = (const float*)d_in[6];
    const float* proj_b = (const float*)d_in[7];
    const float* n2w    = (const float*)d_in[8];
    const float* n2b    = (const float*)d_in[9];
    const float* fc1_w  = (const float*)d_in[10];
    const float* fc1_b  = (const float*)d_in[11];
    const float* fc2_w  = (const float*)d_in[12];
    const float* fc2_b  = (const float*)d_in[13];
    float* out = (float*)d_out;

    ushort* wb   = (ushort*)d_ws;                        // 196608 bf16 weights
    float*  qkvb = (float*)(wb + 196608);                // TOK*384 f32
    ushort* aob  = (ushort*)(qkvb + (size_t)TOK * 384);  // TOK*128 bf16
    float*  x2   = (float*)(aob + (size_t)TOK * CDIM);   // TOK*128 f32
    ushort* hbb  = (ushort*)(x2 + (size_t)TOK * CDIM);   // TOK*512 bf16

    const ushort* w_qkv  = wb;
    const ushort* w_proj = wb + 49152;
    const ushort* w_fc1  = wb + 65536;
    const ushort* w_fc2  = wb + 131072;

    convert_w<<<192, 256, 0, stream>>>(qkv_w, proj_w, fc1_w, fc2_w, wb);
    // LN1 + QKV (q pre-scaled)
    gemm2<384, 128, 0, true><<<dim3(196, 6), 256, 0, stream>>>(
        x, w_qkv, qkv_b, nullptr, n1w, n1b, qkvb, nullptr);
    nat_attn3<<<4 * NHEAD * 49, 256, 0, stream>>>(qkvb, rpb, aob);
    // proj + residual -> x2
    gemm2<128, 128, 1, false><<<dim3(196, 2), 256, 0, stream>>>(
        aob, w_proj, proj_b, x, nullptr, nullptr, x2, nullptr);
    // LN2 + FC1 + GELU -> bf16
    gemm2<512, 128, 2, true><<<dim3(196, 8), 256, 0, stream>>>(
        x2, w_fc1, fc1_b, nullptr, n2w, n2b, nullptr, hbb);
    // FC2 + residual -> out
    gemm2<128, 512, 1, false><<<dim3(196, 2), 256, 0, stream>>>(
        hbb, w_fc2, fc2_b, x2, nullptr, nullptr, out, nullptr);
}

// Round 5
// 91.727 us; speedup vs baseline: 1.1895x; 1.1895x over previous
//
#include <hip/hip_runtime.h>
#include <math.h>

#define TOK 12544   // B*H*W
#define CDIM 128
#define NHEAD 4
#define HD 32
#define KS 7
#define HSZ 56
#define WSZ 56

typedef __attribute__((ext_vector_type(8))) short short8;   // bf16x8 mfma frag
typedef __attribute__((ext_vector_type(4))) float f32x4;

__device__ inline ushort f2b(float f) {                      // fp32 -> bf16 RNE
    uint u = __float_as_uint(f);
    u += 0x7fffu + ((u >> 16) & 1u);
    return (ushort)(u >> 16);
}

// ---------- convert the 4 weight matrices to bf16 into one contiguous buffer ----------
__global__ void convert_w(const float* __restrict__ a, const float* __restrict__ b,
                          const float* __restrict__ c, const float* __restrict__ d,
                          ushort* __restrict__ wb) {
    int e = (blockIdx.x * 256 + threadIdx.x) * 4;
    const float* src;
    if (e < 49152)       src = a + e;
    else if (e < 65536)  src = b + (e - 49152);
    else if (e < 131072) src = c + (e - 65536);
    else                 src = d + (e - 131072);
    float4 v = *(const float4*)src;
    uint2 pk;
    pk.x = (uint)f2b(v.x) | ((uint)f2b(v.y) << 16);
    pk.y = (uint)f2b(v.z) | ((uint)f2b(v.w) << 16);
    *(uint2*)(wb + e) = pk;
}

// ---------- LayerNorm -> bf16 (one wave per 128-elem row) ----------
__global__ void ln_bf16(const float* __restrict__ x, const float* __restrict__ w,
                        const float* __restrict__ b, ushort* __restrict__ y) {
    int row  = blockIdx.x * 4 + (threadIdx.x >> 6);
    int lane = threadIdx.x & 63;
    float2 v = *(const float2*)(x + (size_t)row * CDIM + lane * 2);
    float s = v.x + v.y;
    #pragma unroll
    for (int o = 32; o > 0; o >>= 1) s += __shfl_xor(s, o);
    float mu = s * (1.0f / 128.0f);
    float d0 = v.x - mu, d1 = v.y - mu;
    float sq = d0 * d0 + d1 * d1;
    #pragma unroll
    for (int o = 32; o > 0; o >>= 1) sq += __shfl_xor(sq, o);
    float rstd = rsqrtf(sq * (1.0f / 128.0f) + 1e-5f);
    float2 wv = *(const float2*)(w + lane * 2);
    float2 bv = *(const float2*)(b + lane * 2);
    float o0 = d0 * rstd * wv.x + bv.x;
    float o1 = d1 * rstd * wv.y + bv.y;
    ((uint*)(y + (size_t)row * CDIM))[lane] = (uint)f2b(o0) | ((uint)f2b(o1) << 16);
}

// ---------- MFMA bf16 GEMM (R3 structure, validated) ----------
// EPI: 0 = qkv -> bf16 (scale cols<128 by 32^-0.5); 1 = +res -> f32; 2 = GELU -> bf16
template<int N, int KD, int EPI>
__global__ void gemm_mfma(const ushort* __restrict__ X, const ushort* __restrict__ W,
                          const float* __restrict__ bias, const float* __restrict__ res,
                          float* __restrict__ Yf, ushort* __restrict__ Yb) {
    int wv = threadIdx.x >> 6, lane = threadIdx.x & 63;
    int lr = lane & 15, kg = lane >> 4;
    int m0 = blockIdx.x * 128 + wv * 32;
    int n0 = blockIdx.y * 64;
    f32x4 acc[2][4] = {};
    const ushort* xa = X + (size_t)(m0 + lr) * KD + kg * 8;
    const ushort* xb = xa + (size_t)16 * KD;
    const ushort* wp = W + (size_t)(n0 + lr) * KD + kg * 8;
    #pragma unroll 4
    for (int k0 = 0; k0 < KD; k0 += 32) {
        short8 a0 = *(const short8*)(xa + k0);
        short8 a1 = *(const short8*)(xb + k0);
        #pragma unroll
        for (int ni = 0; ni < 4; ni++) {
            short8 bf = *(const short8*)(wp + (size_t)ni * 16 * KD + k0);
            acc[0][ni] = __builtin_amdgcn_mfma_f32_16x16x32_bf16(a0, bf, acc[0][ni], 0, 0, 0);
            acc[1][ni] = __builtin_amdgcn_mfma_f32_16x16x32_bf16(a1, bf, acc[1][ni], 0, 0, 0);
        }
    }
    #pragma unroll
    for (int mi = 0; mi < 2; mi++)
    #pragma unroll
    for (int ni = 0; ni < 4; ni++) {
        int col = n0 + ni * 16 + lr;
        float bn = bias[col];
        #pragma unroll
        for (int r = 0; r < 4; r++) {
            int row = m0 + mi * 16 + kg * 4 + r;
            size_t o = (size_t)row * N + col;
            float v = acc[mi][ni][r] + bn;
            if (EPI == 0) {
                if (col < CDIM) v *= 0.17677669529663687f;   // q pre-scale 32^-0.5
                Yb[o] = f2b(v);
            } else if (EPI == 1) {
                Yf[o] = v + res[o];
            } else {
                Yb[o] = f2b(0.5f * v * (1.0f + erff(v * 0.70710678118654752f)));
            }
        }
    }
}

// ---------- Neighborhood attention v4: MFMA scores + MFMA PV ----------
// Block per (b, head, 8x8 tile), 4 waves. qkv is bf16 [tok][384] (q pre-scaled).
// Scores S[64pix][208tok] via mfma (Q from global, K halo in LDS, swizzled slots).
// Mask+bias in C-frag epilogue; row softmax via shfl_xor(1,2,4,8); exp -> bf16 att.
// PV via mfma: att[pix][tok] x V^T[d][tok] (V transposed into LDS at staging).
__global__ __launch_bounds__(256) void nat_attn4(const ushort* __restrict__ qkv,
                                                 const float* __restrict__ rpb,
                                                 ushort* __restrict__ ao) {
    __shared__ ushort ks[208 * 32];   // [tok][d], 64B rows, 16B slot c stored at c^(t&3)
    __shared__ ushort vs[32 * 232];   // [d][tok], stride 232 (464B ≡ 20 banks: 2-way, free)
    __shared__ ushort att[64 * 232];  // [pix][tok], stride 232
    __shared__ float rpl[169];

    int tid = threadIdx.x, wv = tid >> 6, lane = tid & 63;
    int lr = lane & 15, kg = lane >> 4;
    int blk = blockIdx.x;
    int tile = blk % 49, hb = blk / 49;
    int head = hb & 3, b = hb >> 2;
    int r0 = (tile / 7) * 8, c0 = (tile % 7) * 8;
    int hr0 = min(max(r0 - 3, 0), HSZ - 14);
    int hc0 = min(max(c0 - 3, 0), WSZ - 14);
    int bimg = b * HSZ * WSZ;

    // ---- phase 0: staging ----
    if (tid < 169) rpl[tid] = rpb[head * 169 + tid];
    // K halo: 196 tokens x 4 chunks of 8 bf16
    for (int idx = tid; idx < 784; idx += 256) {
        int t = idx >> 2, c = idx & 3;
        int gtok = bimg + (hr0 + t / 14) * WSZ + hc0 + t % 14;
        short8 v = *(const short8*)(qkv + (size_t)gtok * 384 + 128 + head * HD + c * 8);
        *(short8*)(ks + t * 32 + ((c ^ (t & 3)) << 3)) = v;
    }
    // V halo transposed into vs[d][t]
    for (int idx = tid; idx < 784; idx += 256) {
        int t = idx >> 2, c = idx & 3;
        int gtok = bimg + (hr0 + t / 14) * WSZ + hc0 + t % 14;
        short8 v = *(const short8*)(qkv + (size_t)gtok * 384 + 256 + head * HD + c * 8);
        #pragma unroll
        for (int q = 0; q < 8; q++) vs[(c * 8 + q) * 232 + t] = (ushort)v[q];
    }
    // zero pads (avoid 0 x NaN-garbage in MFMA): att cols 208..232, vs cols 196..232
    for (int idx = tid; idx < 64 * 12; idx += 256)
        *(uint*)(att + (idx / 12) * 232 + 208 + (idx % 12) * 2) = 0;
    for (int idx = tid; idx < 32 * 18; idx += 256)
        *(uint*)(vs + (idx / 18) * 232 + 196 + (idx % 18) * 2) = 0;
    __syncthreads();

    // ---- phase 1: scores via MFMA ----
    int P0 = wv * 16;
    int apix = P0 + lr;
    int api = apix >> 3, apj = apix & 7;
    int agp = bimg + (r0 + api) * WSZ + c0 + apj;
    short8 aq = *(const short8*)(qkv + (size_t)agp * 384 + head * HD + kg * 8);
    f32x4 sc[13];
    #pragma unroll
    for (int tl = 0; tl < 13; tl++) {
        int t = tl * 16 + lr;
        short8 bk = *(const short8*)(ks + t * 32 + ((kg ^ (t & 3)) << 3));
        f32x4 z = {0.f, 0.f, 0.f, 0.f};
        sc[tl] = __builtin_amdgcn_mfma_f32_16x16x32_bf16(aq, bk, z, 0, 0, 0);
    }

    // ---- phase 2: mask + bias + row softmax; write exp (bf16) to att ----
    float inv[4];
    #pragma unroll
    for (int r = 0; r < 4; r++) {
        int idx = P0 + kg * 4 + r;
        int pi = idx >> 3, pj = idx & 7;
        int i = r0 + pi, j = c0 + pj;
        int shh = min(max(i - 3, 0), HSZ - KS);
        int sww = min(max(j - 3, 0), WSZ - KS);
        int di = shh - hr0, dj = sww - hc0;
        int offh = hr0 - i + 6, offw = hc0 - j + 6;
        float sv[13];
        float mx = -1e30f;
        #pragma unroll
        for (int tl = 0; tl < 13; tl++) {
            int t = tl * 16 + lr;
            int thr = (unsigned)t / 14u;
            int twr = t - thr * 14;
            bool in = ((unsigned)(thr - di) < 7u) && ((unsigned)(twr - dj) < 7u);
            int bidx = (thr + offh) * 13 + (twr + offw);
            bidx = min(max(bidx, 0), 168);
            float s = sc[tl][r] + rpl[bidx];
            sv[tl] = in ? s : -1e30f;
            mx = fmaxf(mx, sv[tl]);
        }
        #pragma unroll
        for (int o = 8; o > 0; o >>= 1) mx = fmaxf(mx, __shfl_xor(mx, o));
        float sum = 0.f;
        #pragma unroll
        for (int tl = 0; tl < 13; tl++) {
            float e = __expf(sv[tl] - mx);
            sum += e;
            att[idx * 232 + tl * 16 + lr] = f2b(e);
        }
        #pragma unroll
        for (int o = 8; o > 0; o >>= 1) sum += __shfl_xor(sum, o);
        inv[r] = 1.0f / sum;
    }
    // att rows [P0,P0+16) written & read by this wave only -> no barrier needed

    // ---- phase 3: PV via MFMA (K dim = 224 tokens, 7 steps) ----
    f32x4 po[2] = {};
    #pragma unroll
    for (int kst = 0; kst < 7; kst++) {
        short8 pa = *(const short8*)(att + (P0 + lr) * 232 + kst * 32 + kg * 8);
        #pragma unroll
        for (int n = 0; n < 2; n++) {
            short8 vb = *(const short8*)(vs + (n * 16 + lr) * 232 + kst * 32 + kg * 8);
            po[n] = __builtin_amdgcn_mfma_f32_16x16x32_bf16(pa, vb, po[n], 0, 0, 0);
        }
    }

    // ---- phase 4: normalized bf16 output ----
    #pragma unroll
    for (int n = 0; n < 2; n++)
    #pragma unroll
    for (int rr = 0; rr < 4; rr++) {
        int idx = P0 + kg * 4 + rr;
        int pi = idx >> 3, pj = idx & 7;
        int gp = bimg + (r0 + pi) * WSZ + c0 + pj;
        ao[(size_t)gp * CDIM + head * HD + n * 16 + lr] = f2b(po[n][rr] * inv[rr]);
    }
}

extern "C" void kernel_launch(void* const* d_in, const int* in_sizes, int n_in,
                              void* d_out, int out_size, void* d_ws, size_t ws_size,
                              hipStream_t stream) {
    const float* x      = (const float*)d_in[0];
    const float* n1w    = (const float*)d_in[1];
    const float* n1b    = (const float*)d_in[2];
    const float* qkv_w  = (const float*)d_in[3];
    const float* qkv_b  = (const float*)d_in[4];
    const float* rpb    = (const float*)d_in[5];
    const float* proj_w = (const float*)d_in[6];
    const float* proj_b = (const float*)d_in[7];
    const float* n2w    = (const float*)d_in[8];
    const float* n2b    = (const float*)d_in[9];
    const float* fc1_w  = (const float*)d_in[10];
    const float* fc1_b  = (const float*)d_in[11];
    const float* fc2_w  = (const float*)d_in[12];
    const float* fc2_b  = (const float*)d_in[13];
    float* out = (float*)d_out;

    ushort* wb   = (ushort*)d_ws;                        // 196608 bf16 weights
    ushort* xnb  = wb + 196608;                          // TOK*128 bf16
    ushort* qkvb = xnb + (size_t)TOK * CDIM;             // TOK*384 bf16 (q scaled)
    ushort* aob  = qkvb + (size_t)TOK * 384;             // TOK*128 bf16
    float*  x2   = (float*)(aob + (size_t)TOK * CDIM);   // TOK*128 f32
    ushort* znb  = (ushort*)(x2 + (size_t)TOK * CDIM);   // TOK*128 bf16
    ushort* hbb  = znb + (size_t)TOK * CDIM;             // TOK*512 bf16

    const ushort* w_qkv  = wb;
    const ushort* w_proj = wb + 49152;
    const ushort* w_fc1  = wb + 65536;
    const ushort* w_fc2  = wb + 131072;

    convert_w<<<192, 256, 0, stream>>>(qkv_w, proj_w, fc1_w, fc2_w, wb);
    ln_bf16<<<TOK / 4, 256, 0, stream>>>(x, n1w, n1b, xnb);
    gemm_mfma<384, 128, 0><<<dim3(98, 6), 256, 0, stream>>>(xnb, w_qkv, qkv_b, nullptr, nullptr, qkvb);
    nat_attn4<<<4 * NHEAD * 49, 256, 0, stream>>>(qkvb, rpb, aob);
    gemm_mfma<128, 128, 1><<<dim3(98, 2), 256, 0, stream>>>(aob, w_proj, proj_b, x, x2, nullptr);
    ln_bf16<<<TOK / 4, 256, 0, stream>>>(x2, n2w, n2b, znb);
    gemm_mfma<512, 128, 2><<<dim3(98, 8), 256, 0, stream>>>(znb, w_fc1, fc1_b, nullptr, nullptr, hbb);
    gemm_mfma<128, 512, 1><<<dim3(98, 2), 256, 0, stream>>>(hbb, w_fc2, fc2_b, x2, out, nullptr);
}

// Round 6
// 73.740 us; speedup vs baseline: 1.4796x; 1.2439x over previous
//
#include <hip/hip_runtime.h>
#include <math.h>

#define TOK 12544   // B*H*W
#define CDIM 128
#define NHEAD 4
#define HD 32
#define KS 7
#define HSZ 56
#define WSZ 56

typedef __attribute__((ext_vector_type(8))) short short8;   // bf16x8 mfma frag
typedef __attribute__((ext_vector_type(4))) float f32x4;

__device__ inline ushort f2b(float f) {                      // fp32 -> bf16 RNE
    uint u = __float_as_uint(f);
    u += 0x7fffu + ((u >> 16) & 1u);
    return (ushort)(u >> 16);
}

// ---------- convert the 4 weight matrices to bf16 into one contiguous buffer ----------
__global__ void convert_w(const float* __restrict__ a, const float* __restrict__ b,
                          const float* __restrict__ c, const float* __restrict__ d,
                          ushort* __restrict__ wb) {
    int e = (blockIdx.x * 256 + threadIdx.x) * 4;
    const float* src;
    if (e < 49152)       src = a + e;
    else if (e < 65536)  src = b + (e - 49152);
    else if (e < 131072) src = c + (e - 65536);
    else                 src = d + (e - 131072);
    float4 v = *(const float4*)src;
    uint2 pk;
    pk.x = (uint)f2b(v.x) | ((uint)f2b(v.y) << 16);
    pk.y = (uint)f2b(v.z) | ((uint)f2b(v.w) << 16);
    *(uint2*)(wb + e) = pk;
}

// ---------- helper: LN of a 64-row tile into swizzled LDS (bf16) ----------
// 8 waves x 8 rows each; lane handles 2 elems. Swizzle: byte ^= ((row&7)<<4).
__device__ inline void ln_to_lds(const float* __restrict__ X, int m0,
                                 const float* __restrict__ lnw, const float* __restrict__ lnb,
                                 ushort* __restrict__ lds) {
    int wv = threadIdx.x >> 6, lane = threadIdx.x & 63;
    #pragma unroll
    for (int r = 0; r < 8; r++) {
        int rl = wv * 8 + r;
        float2 v = *(const float2*)(X + (size_t)(m0 + rl) * CDIM + lane * 2);
        float s = v.x + v.y;
        #pragma unroll
        for (int o = 32; o > 0; o >>= 1) s += __shfl_xor(s, o);
        float mu = s * (1.0f / 128.0f);
        float d0 = v.x - mu, d1 = v.y - mu;
        float sq = d0 * d0 + d1 * d1;
        #pragma unroll
        for (int o = 32; o > 0; o >>= 1) sq += __shfl_xor(sq, o);
        float rstd = rsqrtf(sq * (1.0f / 128.0f) + 1e-5f);
        float2 wv2 = *(const float2*)(lnw + lane * 2);
        float2 bv2 = *(const float2*)(lnb + lane * 2);
        uint pk = (uint)f2b(d0 * rstd * wv2.x + bv2.x)
                | ((uint)f2b(d1 * rstd * wv2.y + bv2.y) << 16);
        *(uint*)((char*)lds + rl * 256 + ((lane * 4) ^ ((rl & 7) << 4))) = pk;
    }
}

// ---------- fused LN1 + QKV GEMM: block = 64 rows x 384 cols, 512 thr ----------
// wave w: 64 rows x cols [w*48, w*48+48). q pre-scaled by 32^-0.5. Out bf16.
__global__ __launch_bounds__(512) void ln1_qkv(const float* __restrict__ X,
                                               const ushort* __restrict__ W,
                                               const float* __restrict__ bias,
                                               const float* __restrict__ lnw,
                                               const float* __restrict__ lnb,
                                               ushort* __restrict__ Y) {
    __shared__ ushort xn[64 * 128];   // 16 KB swizzled
    int m0 = blockIdx.x * 64;
    ln_to_lds(X, m0, lnw, lnb, xn);
    __syncthreads();

    int wv = threadIdx.x >> 6, lane = threadIdx.x & 63;
    int lr = lane & 15, kg = lane >> 4;
    int n0 = wv * 48;
    f32x4 acc[4][3] = {};
    #pragma unroll
    for (int k0 = 0; k0 < 128; k0 += 32) {
        short8 bf[3];
        #pragma unroll
        for (int ni = 0; ni < 3; ni++)
            bf[ni] = *(const short8*)(W + (size_t)(n0 + ni * 16 + lr) * 128 + k0 + kg * 8);
        #pragma unroll
        for (int mg = 0; mg < 4; mg++) {
            int row = mg * 16 + lr;
            short8 a0 = *(const short8*)((char*)xn + row * 256 + ((k0 * 2 + kg * 16) ^ ((row & 7) << 4)));
            #pragma unroll
            for (int ni = 0; ni < 3; ni++)
                acc[mg][ni] = __builtin_amdgcn_mfma_f32_16x16x32_bf16(a0, bf[ni], acc[mg][ni], 0, 0, 0);
        }
    }
    #pragma unroll
    for (int mg = 0; mg < 4; mg++)
    #pragma unroll
    for (int ni = 0; ni < 3; ni++) {
        int col = n0 + ni * 16 + lr;
        float bn = bias[col];
        float sc = (col < CDIM) ? 0.17677669529663687f : 1.0f;
        #pragma unroll
        for (int r = 0; r < 4; r++) {
            int row = m0 + mg * 16 + kg * 4 + r;
            float v = acc[mg][ni][r] + bn;
            if (col < CDIM) v *= sc;
            Y[(size_t)row * 384 + col] = f2b(v);
        }
    }
}

// ---------- proj GEMM: wave tile 16x64, grid (TOK/64, N/64), +bias+residual ----------
template<int N, int KD>
__global__ __launch_bounds__(256) void gemm_proj(const ushort* __restrict__ X,
                                                 const ushort* __restrict__ W,
                                                 const float* __restrict__ bias,
                                                 const float* __restrict__ res,
                                                 float* __restrict__ Yf) {
    int wv = threadIdx.x >> 6, lane = threadIdx.x & 63;
    int lr = lane & 15, kg = lane >> 4;
    int m0 = blockIdx.x * 64 + wv * 16;
    int n0 = blockIdx.y * 64;
    f32x4 acc[4] = {};
    const ushort* xa = X + (size_t)(m0 + lr) * KD + kg * 8;
    const ushort* wp = W + (size_t)(n0 + lr) * KD + kg * 8;
    #pragma unroll
    for (int k0 = 0; k0 < KD; k0 += 32) {
        short8 a0 = *(const short8*)(xa + k0);
        #pragma unroll
        for (int ni = 0; ni < 4; ni++) {
            short8 bf = *(const short8*)(wp + (size_t)ni * 16 * KD + k0);
            acc[ni] = __builtin_amdgcn_mfma_f32_16x16x32_bf16(a0, bf, acc[ni], 0, 0, 0);
        }
    }
    #pragma unroll
    for (int ni = 0; ni < 4; ni++) {
        int col = n0 + ni * 16 + lr;
        float bn = bias[col];
        #pragma unroll
        for (int r = 0; r < 4; r++) {
            int row = m0 + kg * 4 + r;
            size_t o = (size_t)row * N + col;
            Yf[o] = acc[ni][r] + bn + res[o];
        }
    }
}

// ---------- fused MLP: LN2 + FC1 + GELU + FC2 + residual, block = 64 rows ----------
// 512 thr (8 waves). zn[64][128] + hb[64][256] (two 256-col passes) = 48 KB LDS.
__global__ __launch_bounds__(512) void mlp_fused(const float* __restrict__ X2,
                                                 const ushort* __restrict__ W1,
                                                 const float* __restrict__ b1,
                                                 const ushort* __restrict__ W2,
                                                 const float* __restrict__ b2,
                                                 const float* __restrict__ lnw,
                                                 const float* __restrict__ lnb,
                                                 float* __restrict__ out) {
    __shared__ ushort zn[64 * 128];   // 16 KB swizzled
    __shared__ ushort hb[64 * 256];   // 32 KB swizzled
    int m0 = blockIdx.x * 64;
    ln_to_lds(X2, m0, lnw, lnb, zn);

    int wv = threadIdx.x >> 6, lane = threadIdx.x & 63;
    int lr = lane & 15, kg = lane >> 4;
    int rw0 = (wv >> 2) * 32, cw0 = (wv & 3) * 32;   // fc2 wave tile 32x32
    f32x4 acc2[2][2] = {};
    __syncthreads();

    #pragma unroll
    for (int p = 0; p < 2; p++) {
        // ---- fc1 + GELU: wave owns cols [p*256 + wv*32, +32) over all 64 rows ----
        f32x4 acc1[4][2] = {};
        int nc0 = wv * 32;
        #pragma unroll
        for (int k0 = 0; k0 < 128; k0 += 32) {
            short8 bf[2];
            #pragma unroll
            for (int ni = 0; ni < 2; ni++)
                bf[ni] = *(const short8*)(W1 + (size_t)(p * 256 + nc0 + ni * 16 + lr) * 128 + k0 + kg * 8);
            #pragma unroll
            for (int mg = 0; mg < 4; mg++) {
                int row = mg * 16 + lr;
                short8 a0 = *(const short8*)((char*)zn + row * 256 + ((k0 * 2 + kg * 16) ^ ((row & 7) << 4)));
                #pragma unroll
                for (int ni = 0; ni < 2; ni++)
                    acc1[mg][ni] = __builtin_amdgcn_mfma_f32_16x16x32_bf16(a0, bf[ni], acc1[mg][ni], 0, 0, 0);
            }
        }
        #pragma unroll
        for (int mg = 0; mg < 4; mg++)
        #pragma unroll
        for (int ni = 0; ni < 2; ni++) {
            int lc = nc0 + ni * 16 + lr;
            float bn = b1[p * 256 + lc];
            #pragma unroll
            for (int r = 0; r < 4; r++) {
                int row = mg * 16 + kg * 4 + r;
                float v = acc1[mg][ni][r] + bn;
                v = 0.5f * v * (1.0f + erff(v * 0.70710678118654752f));
                *(ushort*)((char*)hb + row * 512 + ((lc * 2) ^ ((row & 7) << 4))) = f2b(v);
            }
        }
        __syncthreads();

        // ---- fc2 partial: K slice [p*256, +256) from hb ----
        #pragma unroll
        for (int k0 = 0; k0 < 256; k0 += 32) {
            short8 a0[2], bf[2];
            #pragma unroll
            for (int mi = 0; mi < 2; mi++) {
                int row = rw0 + mi * 16 + lr;
                a0[mi] = *(const short8*)((char*)hb + row * 512 + ((k0 * 2 + kg * 16) ^ ((row & 7) << 4)));
            }
            #pragma unroll
            for (int ni = 0; ni < 2; ni++)
                bf[ni] = *(const short8*)(W2 + (size_t)(cw0 + ni * 16 + lr) * 512 + p * 256 + k0 + kg * 8);
            #pragma unroll
            for (int mi = 0; mi < 2; mi++)
            #pragma unroll
            for (int ni = 0; ni < 2; ni++)
                acc2[mi][ni] = __builtin_amdgcn_mfma_f32_16x16x32_bf16(a0[mi], bf[ni], acc2[mi][ni], 0, 0, 0);
        }
        __syncthreads();   // protect hb before next pass overwrites
    }

    #pragma unroll
    for (int mi = 0; mi < 2; mi++)
    #pragma unroll
    for (int ni = 0; ni < 2; ni++) {
        int col = cw0 + ni * 16 + lr;
        float bn = b2[col];
        #pragma unroll
        for (int r = 0; r < 4; r++) {
            int row = m0 + rw0 + mi * 16 + kg * 4 + r;
            size_t o = (size_t)row * CDIM + col;
            out[o] = acc2[mi][ni][r] + bn + X2[o];
        }
    }
}

// ---------- Neighborhood attention v4 (validated R5): MFMA scores + MFMA PV ----------
__global__ __launch_bounds__(256) void nat_attn4(const ushort* __restrict__ qkv,
                                                 const float* __restrict__ rpb,
                                                 ushort* __restrict__ ao) {
    __shared__ ushort ks[208 * 32];
    __shared__ ushort vs[32 * 232];
    __shared__ ushort att[64 * 232];
    __shared__ float rpl[169];

    int tid = threadIdx.x, wv = tid >> 6, lane = tid & 63;
    int lr = lane & 15, kg = lane >> 4;
    int blk = blockIdx.x;
    int tile = blk % 49, hb2 = blk / 49;
    int head = hb2 & 3, b = hb2 >> 2;
    int r0 = (tile / 7) * 8, c0 = (tile % 7) * 8;
    int hr0 = min(max(r0 - 3, 0), HSZ - 14);
    int hc0 = min(max(c0 - 3, 0), WSZ - 14);
    int bimg = b * HSZ * WSZ;

    if (tid < 169) rpl[tid] = rpb[head * 169 + tid];
    for (int idx = tid; idx < 784; idx += 256) {
        int t = idx >> 2, c = idx & 3;
        int gtok = bimg + (hr0 + t / 14) * WSZ + hc0 + t % 14;
        short8 v = *(const short8*)(qkv + (size_t)gtok * 384 + 128 + head * HD + c * 8);
        *(short8*)(ks + t * 32 + ((c ^ (t & 3)) << 3)) = v;
    }
    for (int idx = tid; idx < 784; idx += 256) {
        int t = idx >> 2, c = idx & 3;
        int gtok = bimg + (hr0 + t / 14) * WSZ + hc0 + t % 14;
        short8 v = *(const short8*)(qkv + (size_t)gtok * 384 + 256 + head * HD + c * 8);
        #pragma unroll
        for (int q = 0; q < 8; q++) vs[(c * 8 + q) * 232 + t] = (ushort)v[q];
    }
    for (int idx = tid; idx < 64 * 12; idx += 256)
        *(uint*)(att + (idx / 12) * 232 + 208 + (idx % 12) * 2) = 0;
    for (int idx = tid; idx < 32 * 18; idx += 256)
        *(uint*)(vs + (idx / 18) * 232 + 196 + (idx % 18) * 2) = 0;
    __syncthreads();

    int P0 = wv * 16;
    int apix = P0 + lr;
    int agp = bimg + (r0 + (apix >> 3)) * WSZ + c0 + (apix & 7);
    short8 aq = *(const short8*)(qkv + (size_t)agp * 384 + head * HD + kg * 8);
    f32x4 sc[13];
    #pragma unroll
    for (int tl = 0; tl < 13; tl++) {
        int t = tl * 16 + lr;
        short8 bk = *(const short8*)(ks + t * 32 + ((kg ^ (t & 3)) << 3));
        f32x4 z = {0.f, 0.f, 0.f, 0.f};
        sc[tl] = __builtin_amdgcn_mfma_f32_16x16x32_bf16(aq, bk, z, 0, 0, 0);
    }

    float inv[4];
    #pragma unroll
    for (int r = 0; r < 4; r++) {
        int idx = P0 + kg * 4 + r;
        int pi = idx >> 3, pj = idx & 7;
        int i = r0 + pi, j = c0 + pj;
        int shh = min(max(i - 3, 0), HSZ - KS);
        int sww = min(max(j - 3, 0), WSZ - KS);
        int di = shh - hr0, dj = sww - hc0;
        int offh = hr0 - i + 6, offw = hc0 - j + 6;
        float sv[13];
        float mx = -1e30f;
        #pragma unroll
        for (int tl = 0; tl < 13; tl++) {
            int t = tl * 16 + lr;
            int thr = (unsigned)t / 14u;
            int twr = t - thr * 14;
            bool in = ((unsigned)(thr - di) < 7u) && ((unsigned)(twr - dj) < 7u);
            int bidx = (thr + offh) * 13 + (twr + offw);
            bidx = min(max(bidx, 0), 168);
            float s = sc[tl][r] + rpl[bidx];
            sv[tl] = in ? s : -1e30f;
            mx = fmaxf(mx, sv[tl]);
        }
        #pragma unroll
        for (int o = 8; o > 0; o >>= 1) mx = fmaxf(mx, __shfl_xor(mx, o));
        float sum = 0.f;
        #pragma unroll
        for (int tl = 0; tl < 13; tl++) {
            float e = __expf(sv[tl] - mx);
            sum += e;
            att[idx * 232 + tl * 16 + lr] = f2b(e);
        }
        #pragma unroll
        for (int o = 8; o > 0; o >>= 1) sum += __shfl_xor(sum, o);
        inv[r] = 1.0f / sum;
    }

    f32x4 po[2] = {};
    #pragma unroll
    for (int kst = 0; kst < 7; kst++) {
        short8 pa = *(const short8*)(att + (P0 + lr) * 232 + kst * 32 + kg * 8);
        #pragma unroll
        for (int n = 0; n < 2; n++) {
            short8 vb = *(const short8*)(vs + (n * 16 + lr) * 232 + kst * 32 + kg * 8);
            po[n] = __builtin_amdgcn_mfma_f32_16x16x32_bf16(pa, vb, po[n], 0, 0, 0);
        }
    }

    #pragma unroll
    for (int n = 0; n < 2; n++)
    #pragma unroll
    for (int rr = 0; rr < 4; rr++) {
        int idx = P0 + kg * 4 + rr;
        int gp = bimg + (r0 + (idx >> 3)) * WSZ + c0 + (idx & 7);
        ao[(size_t)gp * CDIM + head * HD + n * 16 + lr] = f2b(po[n][rr] * inv[rr]);
    }
}

extern "C" void kernel_launch(void* const* d_in, const int* in_sizes, int n_in,
                              void* d_out, int out_size, void* d_ws, size_t ws_size,
                              hipStream_t stream) {
    const float* x      = (const float*)d_in[0];
    const float* n1w    = (const float*)d_in[1];
    const float* n1b    = (const float*)d_in[2];
    const float* qkv_w  = (const float*)d_in[3];
    const float* qkv_b  = (const float*)d_in[4];
    const float* rpb    = (const float*)d_in[5];
    const float* proj_w = (const float*)d_in[6];
    const float* proj_b = (const float*)d_in[7];
    const float* n2w    = (const float*)d_in[8];
    const float* n2b    = (const float*)d_in[9];
    const float* fc1_w  = (const float*)d_in[10];
    const float* fc1_b  = (const float*)d_in[11];
    const float* fc2_w  = (const float*)d_in[12];
    const float* fc2_b  = (const float*)d_in[13];
    float* out = (float*)d_out;

    ushort* wb   = (ushort*)d_ws;                        // 196608 bf16 weights
    ushort* qkvb = wb + 196608;                          // TOK*384 bf16 (q scaled)
    ushort* aob  = qkvb + (size_t)TOK * 384;             // TOK*128 bf16
    float*  x2   = (float*)(aob + (size_t)TOK * CDIM);   // TOK*128 f32

    const ushort* w_qkv  = wb;
    const ushort* w_proj = wb + 49152;
    const ushort* w_fc1  = wb + 65536;
    const ushort* w_fc2  = wb + 131072;

    convert_w<<<192, 256, 0, stream>>>(qkv_w, proj_w, fc1_w, fc2_w, wb);
    ln1_qkv<<<TOK / 64, 512, 0, stream>>>(x, w_qkv, qkv_b, n1w, n1b, qkvb);
    nat_attn4<<<4 * NHEAD * 49, 256, 0, stream>>>(qkvb, rpb, aob);
    gemm_proj<128, 128><<<dim3(TOK / 64, 2), 256, 0, stream>>>(aob, w_proj, proj_b, x, x2);
    mlp_fused<<<TOK / 64, 512, 0, stream>>>(x2, w_fc1, fc1_b, w_fc2, fc2_b, n2w, n2b, out);
}